// Round 9
// baseline (152.578 us; speedup 1.0000x reference)
//
#include <hip/hip_runtime.h>

// AdaptiveGN_Patches_Hadamart: per-patch GroupNorm + silu-gate, fp32.
// R8: many small independent blocks to fill barrier bubbles.
// 512 thr/block (8-wave rendezvous), one group per block, x register-
// resident across the barrier (asm-pinned scalars; no LDS tile at all) ->
// launch_bounds(512,8) caps VGPR at 64 -> 4 independent blocks/CU
// (32 waves = occupancy ceiling). y streams in phase 2 (R2/R4/R7 proved
// y-prefetch is neutral: TLP hides it). NT stores for out.
// Addresses are compile-time offsets off a0 (R5 scheme):
//   a = a0 + (k>>1)*65536 + (k&1)*8192, cc = k>>1 (static).

constexpr int CHANNELS = 128;
constexpr int HW = 256;
constexpr int NP = 4;
constexpr int G = 32;
constexpr int CPG = CHANNELS / G;          // 4 channels per group
constexpr float EPS = 1e-5f;

typedef float f32x4 __attribute__((ext_vector_type(4)));

__device__ __forceinline__ float fast_gate(float v) {
    // 1 + silu(v) = 1 + v / (1 + exp(-v)); exp(-v) = exp2(-v*log2(e))
    const float e = __builtin_amdgcn_exp2f(v * -1.44269504088896f);
    return 1.0f + v * __builtin_amdgcn_rcpf(1.0f + e);
}

__global__ __launch_bounds__(512, 8)
void gn_patch_gate_kernel(const float* __restrict__ x,
                          const float* __restrict__ y,
                          const float* __restrict__ wgt,
                          const float* __restrict__ bvec,
                          float* __restrict__ out)
{
    __shared__ float red[16];

    const int bid = blockIdx.x;
    const int g  = bid & 31;          // group
    const int pj = (bid >> 5) & 3;    // patch col
    const int pi = (bid >> 7) & 3;    // patch row
    const int b  = bid >> 9;          // batch
    const int tid = threadIdx.x;

    const unsigned base =
        (((unsigned)b * CHANNELS + (unsigned)g * CPG) * HW + (unsigned)pi * 64) * HW
        + (unsigned)pj * 64;
    // 512 threads cover half a 64x64 plane in float4s: row=tid>>4 in [0,32),
    // col4=tid&15; (k&1) selects the half-plane, (k>>1) the channel.
    const unsigned a0 = base + (((unsigned)tid >> 4) << 8) + (((unsigned)tid & 15) << 2);

    // Phase 1: load x into registers (pinned), accumulate sum / sumsq.
    float xr[32];
    float s = 0.f, ss = 0.f;
#pragma unroll
    for (int k = 0; k < 8; ++k) {
        const unsigned a = a0 + (unsigned)((k >> 1) * 65536 + (k & 1) * 8192);
        const float4 v = *reinterpret_cast<const float4*>(x + a);
        float v0 = v.x, v1 = v.y, v2 = v.z, v3 = v.w;
        asm volatile("" : "+v"(v0), "+v"(v1), "+v"(v2), "+v"(v3)); // no remat
        xr[4*k+0] = v0; xr[4*k+1] = v1; xr[4*k+2] = v2; xr[4*k+3] = v3;
        s  += (v0 + v1) + (v2 + v3);
        ss += (v0 * v0 + v1 * v1) + (v2 * v2 + v3 * v3);
    }

    // Wave (64-lane) butterfly reduce, then cross-wave via LDS.
#pragma unroll
    for (int off = 32; off; off >>= 1) {
        s  += __shfl_xor(s, off);
        ss += __shfl_xor(ss, off);
    }
    const int wv = tid >> 6;          // 8 waves
    if ((tid & 63) == 0) { red[wv] = s; red[8 + wv] = ss; }
    __syncthreads();
    float ts = 0.f, tss = 0.f;
#pragma unroll
    for (int q = 0; q < 8; ++q) { ts += red[q]; tss += red[8 + q]; }

    const float inv_n = 1.0f / 16384.0f;
    const float mean = ts * inv_n;
    const float var  = fmaxf(tss * inv_n - mean * mean, 0.f);
    const float rstd = rsqrtf(var + EPS);

    // Per-channel affine folded into scale/shift (cc = k>>1, static).
    float scl[CPG], sft[CPG];
#pragma unroll
    for (int cc = 0; cc < CPG; ++cc) {
        const float wc = wgt[g * CPG + cc];
        scl[cc] = wc * rstd;
        sft[cc] = bvec[g * CPG + cc] - mean * rstd * wc;
    }

    // Phase 2: x from registers, y streamed, NT store.
#pragma unroll
    for (int k = 0; k < 8; ++k) {
        const unsigned a = a0 + (unsigned)((k >> 1) * 65536 + (k & 1) * 8192);
        const int cc = k >> 1;
        const float4 w = *reinterpret_cast<const float4*>(y + a);
        f32x4 o;
        o.x = (xr[4*k+0] * scl[cc] + sft[cc]) * fast_gate(w.x);
        o.y = (xr[4*k+1] * scl[cc] + sft[cc]) * fast_gate(w.y);
        o.z = (xr[4*k+2] * scl[cc] + sft[cc]) * fast_gate(w.z);
        o.w = (xr[4*k+3] * scl[cc] + sft[cc]) * fast_gate(w.w);
        __builtin_nontemporal_store(o, reinterpret_cast<f32x4*>(out + a));
    }
}

extern "C" void kernel_launch(void* const* d_in, const int* in_sizes, int n_in,
                              void* d_out, int out_size, void* d_ws, size_t ws_size,
                              hipStream_t stream) {
    const float* x    = (const float*)d_in[0];
    const float* y    = (const float*)d_in[1];
    const float* wgt  = (const float*)d_in[2];
    const float* bvec = (const float*)d_in[3];
    float* out = (float*)d_out;

    const int B = in_sizes[0] / (CHANNELS * HW * HW);   // 8
    const int nblocks = B * NP * NP * G;                // 4096
    gn_patch_gate_kernel<<<dim3(nblocks), dim3(512), 0, stream>>>(x, y, wgt, bvec, out);
}

// Round 10
// 147.402 us; speedup vs baseline: 1.0351x; 1.0351x over previous
//
#include <hip/hip_runtime.h>

// AdaptiveGN_Patches_Hadamart: per-patch GroupNorm + silu-gate, fp32.
// FINAL (R6 structure, best measured: 147.5 us bench).
// Each block = one (b, pi, pj, group) = 4 ch x 64x64 patch = 16384 floats.
// x staged once in a 64 KB LDS tile (single HBM read of x; R5 proved the
// no-LDS re-read variant costs +128 MB real HBM); 1024-thread blocks:
// 16 waves x 2 blocks/CU (128 KB of 160 KB LDS) = 32 waves/CU ceiling.
// y streamed in phase 2 (R2/R4/R7 proved prefetching it is neutral — TLP
// hides the latency); fast exp2/rcp silu (R1: VALUBusy 33->14%); NT stores.
// Measured: 805 MB demand / 147.5 us = 5.46 TB/s = 87% of the 6.29 TB/s
// copy ceiling — memory roofline for a 2-read:1-write fp32 stream.

constexpr int CHANNELS = 128;
constexpr int HW = 256;
constexpr int NP = 4;
constexpr int G = 32;
constexpr int CPG = CHANNELS / G;          // 4 channels per group
constexpr float EPS = 1e-5f;

typedef float f32x4 __attribute__((ext_vector_type(4)));

__device__ __forceinline__ float fast_gate(float v) {
    // 1 + silu(v) = 1 + v / (1 + exp(-v)); exp(-v) = exp2(-v*log2(e))
    const float e = __builtin_amdgcn_exp2f(v * -1.44269504088896f);
    return 1.0f + v * __builtin_amdgcn_rcpf(1.0f + e);
}

__global__ __launch_bounds__(1024, 8)
void gn_patch_gate_kernel(const float* __restrict__ x,
                          const float* __restrict__ y,
                          const float* __restrict__ wgt,
                          const float* __restrict__ bvec,
                          float* __restrict__ out)
{
    __shared__ float4 xs[4096];     // 64 KB: the whole group's x tile
    __shared__ float red[32];

    const int bid = blockIdx.x;
    const int g  = bid & 31;          // group
    const int pj = (bid >> 5) & 3;    // patch col
    const int pi = (bid >> 7) & 3;    // patch row
    const int b  = bid >> 9;          // batch
    const int tid = threadIdx.x;

    const unsigned base =
        (((unsigned)b * CHANNELS + (unsigned)g * CPG) * HW + (unsigned)pi * 64) * HW
        + (unsigned)pj * 64;
    // 1024 threads cover one full 64x64 plane in float4s:
    // row = tid>>4 in [0,64), col4 = tid&15.
    const unsigned a0 = base + (((unsigned)tid >> 4) << 8) + (((unsigned)tid & 15) << 2);

    // Phase 1: load x (one channel plane per k) -> LDS, accumulate sums.
    float s = 0.f, ss = 0.f;
#pragma unroll
    for (int k = 0; k < 4; ++k) {
        const unsigned a = a0 + (unsigned)(k << 16);        // k * 65536
        const float4 v = *reinterpret_cast<const float4*>(x + a);
        xs[(unsigned)tid + (unsigned)(k << 10)] = v;
        s  += (v.x + v.y) + (v.z + v.w);
        ss += (v.x * v.x + v.y * v.y) + (v.z * v.z + v.w * v.w);
    }

    // Wave (64-lane) butterfly reduce, then cross-wave via LDS.
#pragma unroll
    for (int off = 32; off; off >>= 1) {
        s  += __shfl_xor(s, off);
        ss += __shfl_xor(ss, off);
    }
    const int wv = tid >> 6;          // 16 waves
    if ((tid & 63) == 0) { red[wv] = s; red[16 + wv] = ss; }
    __syncthreads();
    float ts = 0.f, tss = 0.f;
#pragma unroll
    for (int q = 0; q < 16; ++q) { ts += red[q]; tss += red[16 + q]; }

    const float inv_n = 1.0f / 16384.0f;
    const float mean = ts * inv_n;
    const float var  = fmaxf(tss * inv_n - mean * mean, 0.f);
    const float rstd = rsqrtf(var + EPS);

    // Per-channel affine folded into scale/shift (channel index == k).
    float scl[CPG], sft[CPG];
#pragma unroll
    for (int cc = 0; cc < CPG; ++cc) {
        const float wc = wgt[g * CPG + cc];
        scl[cc] = wc * rstd;
        sft[cc] = bvec[g * CPG + cc] - mean * rstd * wc;
    }

    // Phase 2: normalize from LDS, gate with y, NT store.
#pragma unroll
    for (int k = 0; k < 4; ++k) {
        const unsigned a = a0 + (unsigned)(k << 16);
        const float4 v = xs[(unsigned)tid + (unsigned)(k << 10)];
        const float4 w = *reinterpret_cast<const float4*>(y + a);
        f32x4 o;
        o.x = (v.x * scl[k] + sft[k]) * fast_gate(w.x);
        o.y = (v.y * scl[k] + sft[k]) * fast_gate(w.y);
        o.z = (v.z * scl[k] + sft[k]) * fast_gate(w.z);
        o.w = (v.w * scl[k] + sft[k]) * fast_gate(w.w);
        __builtin_nontemporal_store(o, reinterpret_cast<f32x4*>(out + a));
    }
}

extern "C" void kernel_launch(void* const* d_in, const int* in_sizes, int n_in,
                              void* d_out, int out_size, void* d_ws, size_t ws_size,
                              hipStream_t stream) {
    const float* x    = (const float*)d_in[0];
    const float* y    = (const float*)d_in[1];
    const float* wgt  = (const float*)d_in[2];
    const float* bvec = (const float*)d_in[3];
    float* out = (float*)d_out;

    const int B = in_sizes[0] / (CHANNELS * HW * HW);   // 8
    const int nblocks = B * NP * NP * G;                // 4096
    gn_patch_gate_kernel<<<dim3(nblocks), dim3(1024), 0, stream>>>(x, y, wgt, bvec, out);
}